// Round 1
// baseline (864.413 us; speedup 1.0000x reference)
//
#include <hip/hip_runtime.h>
#include <hip/hip_bf16.h>

// Problem constants (fixed by the harness's setup_inputs)
#define E_ 8
#define D_ 1024
#define H_ 4096
#define N_ 8192

typedef __attribute__((ext_vector_type(8))) short bf16x8;   // MFMA A/B frag: 8 bf16 = 4 VGPRs
typedef __attribute__((ext_vector_type(4))) float f32x4;    // MFMA C/D frag

// fp32 -> bf16 round-to-nearest-even (matches .astype(bfloat16))
static __device__ __forceinline__ unsigned short f2bf(float f) {
    unsigned int u = __float_as_uint(f);
    u += 0x7fffu + ((u >> 16) & 1u);
    return (unsigned short)(u >> 16);
}

static __device__ __forceinline__ void st_bf4(unsigned short* p, float4 v) {
    union { unsigned short u[4]; unsigned long long ll; } t;
    t.u[0] = f2bf(v.x); t.u[1] = f2bf(v.y); t.u[2] = f2bf(v.z); t.u[3] = f2bf(v.w);
    *(unsigned long long*)p = t.ll;
}

// tanh-approx gelu, stable for large |x|
static __device__ __forceinline__ float gelu_tanh(float x) {
    float x3 = x * x * x;
    float z = 0.7978845608028654f * (x + 0.044715f * x3);
    float t = 1.0f - 2.0f / (1.0f + __expf(2.0f * z));  // tanh(z)
    return 0.5f * x * (1.0f + t);
}

static __device__ __forceinline__ int expert_of(const int* __restrict__ ntpe, int row) {
    int acc = 0;
    #pragma unroll
    for (int i = 0; i < E_; ++i) {
        acc += ntpe[i];
        if (row < acc) return i;
    }
    return E_ - 1;
}

// LDS row pitch: 32 bf16 + 8 pad = 40 elements (80 B) -> 16B-aligned rows, <=2-way bank conflicts
#define LDSP 40

// ---------------------------------------------------------------------------
// Kernel 1: h[t, n] = gelu_tanh(x @ w1[e]^T) * (x @ w3[e]^T), h stored bf16
// Tile: BM=128 (tokens) x BN=128 (H dim), BK=32. 256 threads = 4 waves (2x2 of 64x64).
// ---------------------------------------------------------------------------
__global__ __launch_bounds__(256, 2) void moe_gemm13(
    const float* __restrict__ x, const float* __restrict__ w1,
    const float* __restrict__ w3, const int* __restrict__ ntpe,
    unsigned short* __restrict__ hbuf)
{
    const int tid = threadIdx.x;
    const int m0 = blockIdx.y * 128;   // token block
    const int n0 = blockIdx.x * 128;   // H block
    const int e = expert_of(ntpe, m0);

    __shared__ unsigned short sA[128][LDSP];
    __shared__ unsigned short sB1[128][LDSP];
    __shared__ unsigned short sB2[128][LDSP];

    const int wave = tid >> 6, lane = tid & 63;
    const int wm = (wave >> 1) * 64, wn = (wave & 1) * 64;
    const int fr = lane & 15;       // frag non-K index
    const int quad = lane >> 4;     // K sub-offset = quad*8

    f32x4 accg[4][4], accu[4][4];
    #pragma unroll
    for (int i = 0; i < 4; ++i)
        #pragma unroll
        for (int j = 0; j < 4; ++j) {
            accg[i][j] = (f32x4){0.f, 0.f, 0.f, 0.f};
            accu[i][j] = (f32x4){0.f, 0.f, 0.f, 0.f};
        }

    const float* Ab  = x  + (size_t)m0 * D_;
    const float* B1b = w1 + ((size_t)e * H_ + n0) * D_;
    const float* B2b = w3 + ((size_t)e * H_ + n0) * D_;

    for (int k0 = 0; k0 < D_; k0 += 32) {
        // Stage fp32 -> bf16 into LDS. 128x32 per tile = 4096 el; 4 passes x 256 thr x 4 el.
        #pragma unroll
        for (int s = 0; s < 4; ++s) {
            int idx = s * 256 + tid;
            int row = idx >> 3;
            int col = (idx & 7) * 4;
            size_t go = (size_t)row * D_ + k0 + col;
            float4 va = *(const float4*)(Ab  + go);
            float4 v1 = *(const float4*)(B1b + go);
            float4 v2 = *(const float4*)(B2b + go);
            st_bf4(&sA[row][col],  va);
            st_bf4(&sB1[row][col], v1);
            st_bf4(&sB2[row][col], v2);
        }
        __syncthreads();

        bf16x8 fa[4], fb1[4], fb2[4];
        #pragma unroll
        for (int i = 0; i < 4; ++i) {
            fa[i]  = *(const bf16x8*)(&sA[wm + i * 16 + fr][quad * 8]);
            fb1[i] = *(const bf16x8*)(&sB1[wn + i * 16 + fr][quad * 8]);
            fb2[i] = *(const bf16x8*)(&sB2[wn + i * 16 + fr][quad * 8]);
        }
        #pragma unroll
        for (int i = 0; i < 4; ++i)
            #pragma unroll
            for (int j = 0; j < 4; ++j) {
                accg[i][j] = __builtin_amdgcn_mfma_f32_16x16x32_bf16(fa[i], fb1[j], accg[i][j], 0, 0, 0);
                accu[i][j] = __builtin_amdgcn_mfma_f32_16x16x32_bf16(fa[i], fb2[j], accu[i][j], 0, 0, 0);
            }
        __syncthreads();
    }

    // Epilogue: h = gelu(g) * u, cast bf16, store
    #pragma unroll
    for (int i = 0; i < 4; ++i) {
        int rowb = m0 + wm + i * 16 + quad * 4;
        #pragma unroll
        for (int j = 0; j < 4; ++j) {
            int col = n0 + wn + j * 16 + fr;
            #pragma unroll
            for (int r = 0; r < 4; ++r) {
                float hv = gelu_tanh(accg[i][j][r]) * accu[i][j][r];
                hbuf[(size_t)(rowb + r) * H_ + col] = f2bf(hv);
            }
        }
    }
}

// ---------------------------------------------------------------------------
// Kernel 2: out[t, d] = h[t, :] @ w2[e][d, :]  (K = H = 4096), out fp32
// ---------------------------------------------------------------------------
__global__ __launch_bounds__(256, 2) void moe_gemm2(
    const unsigned short* __restrict__ hbuf, const float* __restrict__ w2,
    const int* __restrict__ ntpe, float* __restrict__ out)
{
    const int tid = threadIdx.x;
    const int m0 = blockIdx.y * 128;   // token block
    const int n0 = blockIdx.x * 128;   // D block
    const int e = expert_of(ntpe, m0);

    __shared__ unsigned short sA[128][LDSP];
    __shared__ unsigned short sB[128][LDSP];

    const int wave = tid >> 6, lane = tid & 63;
    const int wm = (wave >> 1) * 64, wn = (wave & 1) * 64;
    const int fr = lane & 15;
    const int quad = lane >> 4;

    f32x4 acc[4][4];
    #pragma unroll
    for (int i = 0; i < 4; ++i)
        #pragma unroll
        for (int j = 0; j < 4; ++j)
            acc[i][j] = (f32x4){0.f, 0.f, 0.f, 0.f};

    const unsigned short* Ab = hbuf + (size_t)m0 * H_;
    const float* Bb = w2 + ((size_t)e * D_ + n0) * H_;

    for (int k0 = 0; k0 < H_; k0 += 32) {
        // A: already bf16. 4096 el; 2 passes x 256 thr x 8 el (16B loads).
        #pragma unroll
        for (int s = 0; s < 2; ++s) {
            int idx = s * 256 + tid;
            int row = idx >> 2;
            int col = (idx & 3) * 8;
            bf16x8 v = *(const bf16x8*)(Ab + (size_t)row * H_ + k0 + col);
            *(bf16x8*)(&sA[row][col]) = v;
        }
        // B: fp32 -> bf16
        #pragma unroll
        for (int s = 0; s < 4; ++s) {
            int idx = s * 256 + tid;
            int row = idx >> 3;
            int col = (idx & 7) * 4;
            float4 v = *(const float4*)(Bb + (size_t)row * H_ + k0 + col);
            st_bf4(&sB[row][col], v);
        }
        __syncthreads();

        bf16x8 fa[4], fb[4];
        #pragma unroll
        for (int i = 0; i < 4; ++i) {
            fa[i] = *(const bf16x8*)(&sA[wm + i * 16 + fr][quad * 8]);
            fb[i] = *(const bf16x8*)(&sB[wn + i * 16 + fr][quad * 8]);
        }
        #pragma unroll
        for (int i = 0; i < 4; ++i)
            #pragma unroll
            for (int j = 0; j < 4; ++j)
                acc[i][j] = __builtin_amdgcn_mfma_f32_16x16x32_bf16(fa[i], fb[j], acc[i][j], 0, 0, 0);
        __syncthreads();
    }

    #pragma unroll
    for (int i = 0; i < 4; ++i) {
        int rowb = m0 + wm + i * 16 + quad * 4;
        #pragma unroll
        for (int j = 0; j < 4; ++j) {
            int col = n0 + wn + j * 16 + fr;
            #pragma unroll
            for (int r = 0; r < 4; ++r)
                out[(size_t)(rowb + r) * D_ + col] = acc[i][j][r];
        }
    }
}

extern "C" void kernel_launch(void* const* d_in, const int* in_sizes, int n_in,
                              void* d_out, int out_size, void* d_ws, size_t ws_size,
                              hipStream_t stream) {
    const float* x  = (const float*)d_in[0];
    const float* w1 = (const float*)d_in[1];
    const float* w2 = (const float*)d_in[2];
    const float* w3 = (const float*)d_in[3];
    const int* ntpe = (const int*)d_in[4];
    float* out = (float*)d_out;
    unsigned short* hbuf = (unsigned short*)d_ws;  // N x H bf16 = 64 MB

    dim3 g1(H_ / 128, N_ / 128);  // (32, 64)
    moe_gemm13<<<g1, 256, 0, stream>>>(x, w1, w3, ntpe, hbuf);

    dim3 g2(D_ / 128, N_ / 128);  // (8, 64)
    moe_gemm2<<<g2, 256, 0, stream>>>(hbuf, w2, ntpe, out);
}

// Round 2
// 740.099 us; speedup vs baseline: 1.1680x; 1.1680x over previous
//
#include <hip/hip_runtime.h>
#include <hip/hip_bf16.h>

#define E_ 8
#define D_ 1024
#define H_ 4096
#define N_ 8192

typedef __attribute__((ext_vector_type(8))) short bf16x8;   // MFMA A/B frag: 8 bf16 = 4 VGPRs
typedef __attribute__((ext_vector_type(4))) float f32x4;    // MFMA C/D frag
typedef unsigned short u16;

// fp32 -> bf16 round-to-nearest-even
static __device__ __forceinline__ u16 f2bf(float f) {
    unsigned int u = __float_as_uint(f);
    u += 0x7fffu + ((u >> 16) & 1u);
    return (u16)(u >> 16);
}

static __device__ __forceinline__ void st_bf4(u16* p, float4 v) {
    union { u16 u[4]; unsigned long long ll; } t;
    t.u[0] = f2bf(v.x); t.u[1] = f2bf(v.y); t.u[2] = f2bf(v.z); t.u[3] = f2bf(v.w);
    *(unsigned long long*)p = t.ll;
}

static __device__ __forceinline__ float gelu_tanh(float x) {
    float x3 = x * x * x;
    float z = 0.7978845608028654f * (x + 0.044715f * x3);
    float t = 1.0f - 2.0f / (1.0f + __expf(2.0f * z));  // tanh(z)
    return 0.5f * x * (1.0f + t);
}

static __device__ __forceinline__ int expert_of(const int* __restrict__ ntpe, int row) {
    int acc = 0;
    #pragma unroll
    for (int i = 0; i < E_; ++i) {
        acc += ntpe[i];
        if (row < acc) return i;
    }
    return E_ - 1;
}

// async 16B/lane global -> LDS. lds base must be wave-uniform; data lands at base + lane*16.
#define GLD16(gp, lp) __builtin_amdgcn_global_load_lds( \
    (const __attribute__((address_space(1))) void*)(gp), \
    (__attribute__((address_space(3))) void*)(lp), 16, 0, 0)

// ---------------------------------------------------------------------------
// Prepass: cast x, w1, w2, w3 fp32 -> bf16 into workspace
// ---------------------------------------------------------------------------
__global__ __launch_bounds__(256) void cvt_all(
    const float* __restrict__ x, const float* __restrict__ w1,
    const float* __restrict__ w2, const float* __restrict__ w3,
    u16* __restrict__ xb, u16* __restrict__ w1b,
    u16* __restrict__ w2b, u16* __restrict__ w3b)
{
    const float* srcs[4] = {x, w1, w2, w3};
    u16* dsts[4] = {xb, w1b, w2b, w3b};
    const int cnt4[4] = {N_ * D_ / 4, E_ * H_ * D_ / 4, E_ * D_ * H_ / 4, E_ * H_ * D_ / 4};
    int gtid = blockIdx.x * 256 + threadIdx.x;
    int gstride = gridDim.x * 256;
    #pragma unroll
    for (int s = 0; s < 4; ++s) {
        const float4* src = (const float4*)srcs[s];
        u16* dst = dsts[s];
        for (int i = gtid; i < cnt4[s]; i += gstride) {
            float4 v = src[i];
            st_bf4(dst + (size_t)i * 4, v);
        }
    }
}

// ---------------------------------------------------------------------------
// Fast kernel 1: h = gelu_tanh(x@w1^T) * (x@w3^T), all operands bf16 in HBM.
// m97 structure: 128x128 tile, BK=32, global_load_lds width 16, unpadded LDS.
// ---------------------------------------------------------------------------
__global__ __launch_bounds__(256, 2) void moe_gemm13_fast(
    const u16* __restrict__ xb, const u16* __restrict__ w1b,
    const u16* __restrict__ w3b, const int* __restrict__ ntpe,
    u16* __restrict__ hbuf)
{
    __shared__ u16 sA[128 * 32], sB1[128 * 32], sB2[128 * 32];
    const int tid = threadIdx.x;
    const int m0 = blockIdx.y * 128, n0 = blockIdx.x * 128;
    const int e = expert_of(ntpe, m0);
    const int wave = tid >> 6, lane = tid & 63;
    const int wm = (wave >> 1) * 64, wn = (wave & 1) * 64;
    const int fr = lane & 15, quad = lane >> 4;

    const u16* Ag  = xb  + (size_t)m0 * D_;
    const u16* B1g = w1b + ((size_t)e * H_ + n0) * D_;
    const u16* B2g = w3b + ((size_t)e * H_ + n0) * D_;

    // staging geometry: wave w, call c covers tile rows [(w*2+c)*16, +16); 4 lanes per 64B row
    const int srow = wave * 32 + (lane >> 2);   // + c*16
    const int scol = (lane & 3) * 8;            // bf16 elements

    f32x4 accg[4][4], accu[4][4];
    #pragma unroll
    for (int i = 0; i < 4; ++i)
        #pragma unroll
        for (int j = 0; j < 4; ++j) {
            accg[i][j] = (f32x4){0.f, 0.f, 0.f, 0.f};
            accu[i][j] = (f32x4){0.f, 0.f, 0.f, 0.f};
        }

    for (int k0 = 0; k0 < D_; k0 += 32) {
        #pragma unroll
        for (int c = 0; c < 2; ++c) {
            size_t go = (size_t)(srow + c * 16) * D_ + k0 + scol;
            int lb = (wave * 2 + c) * 16 * 32;   // wave-uniform LDS base (elements)
            GLD16(Ag + go,  &sA[lb]);
            GLD16(B1g + go, &sB1[lb]);
            GLD16(B2g + go, &sB2[lb]);
        }
        __syncthreads();

        bf16x8 fa[4], fb1[4], fb2[4];
        #pragma unroll
        for (int i = 0; i < 4; ++i) {
            fa[i]  = *(const bf16x8*)(&sA [(wm + i * 16 + fr) * 32 + quad * 8]);
            fb1[i] = *(const bf16x8*)(&sB1[(wn + i * 16 + fr) * 32 + quad * 8]);
            fb2[i] = *(const bf16x8*)(&sB2[(wn + i * 16 + fr) * 32 + quad * 8]);
        }
        #pragma unroll
        for (int i = 0; i < 4; ++i)
            #pragma unroll
            for (int j = 0; j < 4; ++j) {
                accg[i][j] = __builtin_amdgcn_mfma_f32_16x16x32_bf16(fa[i], fb1[j], accg[i][j], 0, 0, 0);
                accu[i][j] = __builtin_amdgcn_mfma_f32_16x16x32_bf16(fa[i], fb2[j], accu[i][j], 0, 0, 0);
            }
        __syncthreads();
    }

    #pragma unroll
    for (int i = 0; i < 4; ++i) {
        int rowb = m0 + wm + i * 16 + quad * 4;
        #pragma unroll
        for (int j = 0; j < 4; ++j) {
            int col = n0 + wn + j * 16 + fr;
            #pragma unroll
            for (int r = 0; r < 4; ++r) {
                float hv = gelu_tanh(accg[i][j][r]) * accu[i][j][r];
                hbuf[(size_t)(rowb + r) * H_ + col] = f2bf(hv);
            }
        }
    }
}

// ---------------------------------------------------------------------------
// Fast kernel 2: out = h @ w2^T (K = 4096), h and w2 bf16 in HBM, out fp32
// ---------------------------------------------------------------------------
__global__ __launch_bounds__(256, 2) void moe_gemm2_fast(
    const u16* __restrict__ hbuf, const u16* __restrict__ w2b,
    const int* __restrict__ ntpe, float* __restrict__ out)
{
    __shared__ u16 sA[128 * 32], sB[128 * 32];
    const int tid = threadIdx.x;
    const int m0 = blockIdx.y * 128, n0 = blockIdx.x * 128;
    const int e = expert_of(ntpe, m0);
    const int wave = tid >> 6, lane = tid & 63;
    const int wm = (wave >> 1) * 64, wn = (wave & 1) * 64;
    const int fr = lane & 15, quad = lane >> 4;

    const u16* Ag = hbuf + (size_t)m0 * H_;
    const u16* Bg = w2b + ((size_t)e * D_ + n0) * H_;

    const int srow = wave * 32 + (lane >> 2);
    const int scol = (lane & 3) * 8;

    f32x4 acc[4][4];
    #pragma unroll
    for (int i = 0; i < 4; ++i)
        #pragma unroll
        for (int j = 0; j < 4; ++j)
            acc[i][j] = (f32x4){0.f, 0.f, 0.f, 0.f};

    for (int k0 = 0; k0 < H_; k0 += 32) {
        #pragma unroll
        for (int c = 0; c < 2; ++c) {
            size_t go = (size_t)(srow + c * 16) * H_ + k0 + scol;
            int lb = (wave * 2 + c) * 16 * 32;
            GLD16(Ag + go, &sA[lb]);
            GLD16(Bg + go, &sB[lb]);
        }
        __syncthreads();

        bf16x8 fa[4], fb[4];
        #pragma unroll
        for (int i = 0; i < 4; ++i) {
            fa[i] = *(const bf16x8*)(&sA[(wm + i * 16 + fr) * 32 + quad * 8]);
            fb[i] = *(const bf16x8*)(&sB[(wn + i * 16 + fr) * 32 + quad * 8]);
        }
        #pragma unroll
        for (int i = 0; i < 4; ++i)
            #pragma unroll
            for (int j = 0; j < 4; ++j)
                acc[i][j] = __builtin_amdgcn_mfma_f32_16x16x32_bf16(fa[i], fb[j], acc[i][j], 0, 0, 0);
        __syncthreads();
    }

    #pragma unroll
    for (int i = 0; i < 4; ++i) {
        int rowb = m0 + wm + i * 16 + quad * 4;
        #pragma unroll
        for (int j = 0; j < 4; ++j) {
            int col = n0 + wn + j * 16 + fr;
            #pragma unroll
            for (int r = 0; r < 4; ++r)
                out[(size_t)(rowb + r) * D_ + col] = acc[i][j][r];
        }
    }
}

// ---------------------------------------------------------------------------
// Fallback (round-1) kernels: fused fp32->bf16 staging, used if ws too small
// ---------------------------------------------------------------------------
#define LDSP 40

__global__ __launch_bounds__(256, 2) void moe_gemm13_slow(
    const float* __restrict__ x, const float* __restrict__ w1,
    const float* __restrict__ w3, const int* __restrict__ ntpe,
    u16* __restrict__ hbuf)
{
    const int tid = threadIdx.x;
    const int m0 = blockIdx.y * 128, n0 = blockIdx.x * 128;
    const int e = expert_of(ntpe, m0);
    __shared__ u16 sA[128][LDSP]; __shared__ u16 sB1[128][LDSP]; __shared__ u16 sB2[128][LDSP];
    const int wave = tid >> 6, lane = tid & 63;
    const int wm = (wave >> 1) * 64, wn = (wave & 1) * 64;
    const int fr = lane & 15, quad = lane >> 4;
    f32x4 accg[4][4], accu[4][4];
    #pragma unroll
    for (int i = 0; i < 4; ++i)
        #pragma unroll
        for (int j = 0; j < 4; ++j) {
            accg[i][j] = (f32x4){0.f,0.f,0.f,0.f}; accu[i][j] = (f32x4){0.f,0.f,0.f,0.f};
        }
    const float* Ab  = x  + (size_t)m0 * D_;
    const float* B1b = w1 + ((size_t)e * H_ + n0) * D_;
    const float* B2b = w3 + ((size_t)e * H_ + n0) * D_;
    for (int k0 = 0; k0 < D_; k0 += 32) {
        #pragma unroll
        for (int s = 0; s < 4; ++s) {
            int idx = s * 256 + tid;
            int row = idx >> 3, col = (idx & 7) * 4;
            size_t go = (size_t)row * D_ + k0 + col;
            st_bf4(&sA[row][col],  *(const float4*)(Ab + go));
            st_bf4(&sB1[row][col], *(const float4*)(B1b + go));
            st_bf4(&sB2[row][col], *(const float4*)(B2b + go));
        }
        __syncthreads();
        bf16x8 fa[4], fb1[4], fb2[4];
        #pragma unroll
        for (int i = 0; i < 4; ++i) {
            fa[i]  = *(const bf16x8*)(&sA[wm + i * 16 + fr][quad * 8]);
            fb1[i] = *(const bf16x8*)(&sB1[wn + i * 16 + fr][quad * 8]);
            fb2[i] = *(const bf16x8*)(&sB2[wn + i * 16 + fr][quad * 8]);
        }
        #pragma unroll
        for (int i = 0; i < 4; ++i)
            #pragma unroll
            for (int j = 0; j < 4; ++j) {
                accg[i][j] = __builtin_amdgcn_mfma_f32_16x16x32_bf16(fa[i], fb1[j], accg[i][j], 0, 0, 0);
                accu[i][j] = __builtin_amdgcn_mfma_f32_16x16x32_bf16(fa[i], fb2[j], accu[i][j], 0, 0, 0);
            }
        __syncthreads();
    }
    #pragma unroll
    for (int i = 0; i < 4; ++i) {
        int rowb = m0 + wm + i * 16 + quad * 4;
        #pragma unroll
        for (int j = 0; j < 4; ++j) {
            int col = n0 + wn + j * 16 + fr;
            #pragma unroll
            for (int r = 0; r < 4; ++r)
                hbuf[(size_t)(rowb + r) * H_ + col] = f2bf(gelu_tanh(accg[i][j][r]) * accu[i][j][r]);
        }
    }
}

__global__ __launch_bounds__(256, 2) void moe_gemm2_slow(
    const u16* __restrict__ hbuf, const float* __restrict__ w2,
    const int* __restrict__ ntpe, float* __restrict__ out)
{
    const int tid = threadIdx.x;
    const int m0 = blockIdx.y * 128, n0 = blockIdx.x * 128;
    const int e = expert_of(ntpe, m0);
    __shared__ u16 sA[128][LDSP]; __shared__ u16 sB[128][LDSP];
    const int wave = tid >> 6, lane = tid & 63;
    const int wm = (wave >> 1) * 64, wn = (wave & 1) * 64;
    const int fr = lane & 15, quad = lane >> 4;
    f32x4 acc[4][4];
    #pragma unroll
    for (int i = 0; i < 4; ++i)
        #pragma unroll
        for (int j = 0; j < 4; ++j) acc[i][j] = (f32x4){0.f,0.f,0.f,0.f};
    const u16* Ab = hbuf + (size_t)m0 * H_;
    const float* Bb = w2 + ((size_t)e * D_ + n0) * H_;
    for (int k0 = 0; k0 < H_; k0 += 32) {
        #pragma unroll
        for (int s = 0; s < 2; ++s) {
            int idx = s * 256 + tid;
            int row = idx >> 2, col = (idx & 3) * 8;
            *(bf16x8*)(&sA[row][col]) = *(const bf16x8*)(Ab + (size_t)row * H_ + k0 + col);
        }
        #pragma unroll
        for (int s = 0; s < 4; ++s) {
            int idx = s * 256 + tid;
            int row = idx >> 3, col = (idx & 7) * 4;
            st_bf4(&sB[row][col], *(const float4*)(Bb + (size_t)row * H_ + k0 + col));
        }
        __syncthreads();
        bf16x8 fa[4], fb[4];
        #pragma unroll
        for (int i = 0; i < 4; ++i) {
            fa[i] = *(const bf16x8*)(&sA[wm + i * 16 + fr][quad * 8]);
            fb[i] = *(const bf16x8*)(&sB[wn + i * 16 + fr][quad * 8]);
        }
        #pragma unroll
        for (int i = 0; i < 4; ++i)
            #pragma unroll
            for (int j = 0; j < 4; ++j)
                acc[i][j] = __builtin_amdgcn_mfma_f32_16x16x32_bf16(fa[i], fb[j], acc[i][j], 0, 0, 0);
        __syncthreads();
    }
    #pragma unroll
    for (int i = 0; i < 4; ++i) {
        int rowb = m0 + wm + i * 16 + quad * 4;
        #pragma unroll
        for (int j = 0; j < 4; ++j) {
            int col = n0 + wn + j * 16 + fr;
            #pragma unroll
            for (int r = 0; r < 4; ++r)
                out[(size_t)(rowb + r) * D_ + col] = acc[i][j][r];
        }
    }
}

extern "C" void kernel_launch(void* const* d_in, const int* in_sizes, int n_in,
                              void* d_out, int out_size, void* d_ws, size_t ws_size,
                              hipStream_t stream) {
    const float* x  = (const float*)d_in[0];
    const float* w1 = (const float*)d_in[1];
    const float* w2 = (const float*)d_in[2];
    const float* w3 = (const float*)d_in[3];
    const int* ntpe = (const int*)d_in[4];
    float* out = (float*)d_out;

    // ws layout (bytes): xb 16M | w1b 64M | w3b 64M | w2b 64M | h 64M = 272 MB
    const size_t SZ_XB = (size_t)N_ * D_ * 2;
    const size_t SZ_W  = (size_t)E_ * H_ * D_ * 2;
    const size_t SZ_H  = (size_t)N_ * H_ * 2;
    const size_t NEED  = SZ_XB + 3 * SZ_W + SZ_H;

    if (ws_size >= NEED) {
        char* p = (char*)d_ws;
        u16* xb  = (u16*)p;                 p += SZ_XB;
        u16* w1b = (u16*)p;                 p += SZ_W;
        u16* w3b = (u16*)p;                 p += SZ_W;
        u16* w2b = (u16*)p;                 p += SZ_W;
        u16* hb  = (u16*)p;

        cvt_all<<<4096, 256, 0, stream>>>(x, w1, w2, w3, xb, w1b, w2b, w3b);

        dim3 g1(H_ / 128, N_ / 128);  // (32, 64)
        moe_gemm13_fast<<<g1, 256, 0, stream>>>(xb, w1b, w3b, ntpe, hb);

        dim3 g2(D_ / 128, N_ / 128);  // (8, 64)
        moe_gemm2_fast<<<g2, 256, 0, stream>>>(hb, w2b, ntpe, out);
    } else {
        u16* hb = (u16*)d_ws;  // 64 MB
        dim3 g1(H_ / 128, N_ / 128);
        moe_gemm13_slow<<<g1, 256, 0, stream>>>(x, w1, w3, ntpe, hb);
        dim3 g2(D_ / 128, N_ / 128);
        moe_gemm2_slow<<<g2, 256, 0, stream>>>(hb, w2, ntpe, out);
    }
}

// Round 3
// 705.478 us; speedup vs baseline: 1.2253x; 1.0491x over previous
//
#include <hip/hip_runtime.h>
#include <hip/hip_bf16.h>

#define E_ 8
#define D_ 1024
#define H_ 4096
#define N_ 8192

typedef __attribute__((ext_vector_type(8))) short bf16x8;   // MFMA A/B frag: 8 bf16 = 4 VGPRs
typedef __attribute__((ext_vector_type(4))) float f32x4;    // MFMA C/D frag
typedef unsigned short u16;

// fp32 -> bf16 round-to-nearest-even
static __device__ __forceinline__ u16 f2bf(float f) {
    unsigned int u = __float_as_uint(f);
    u += 0x7fffu + ((u >> 16) & 1u);
    return (u16)(u >> 16);
}

static __device__ __forceinline__ void st_bf4(u16* p, float4 v) {
    union { u16 u[4]; unsigned long long ll; } t;
    t.u[0] = f2bf(v.x); t.u[1] = f2bf(v.y); t.u[2] = f2bf(v.z); t.u[3] = f2bf(v.w);
    *(unsigned long long*)p = t.ll;
}

static __device__ __forceinline__ float gelu_tanh(float x) {
    float x3 = x * x * x;
    float z = 0.7978845608028654f * (x + 0.044715f * x3);
    float t = 1.0f - 2.0f / (1.0f + __expf(2.0f * z));  // tanh(z)
    return 0.5f * x * (1.0f + t);
}

static __device__ __forceinline__ int expert_of(const int* __restrict__ ntpe, int row) {
    int acc = 0;
    #pragma unroll
    for (int i = 0; i < E_; ++i) {
        acc += ntpe[i];
        if (row < acc) return i;
    }
    return E_ - 1;
}

// async 16B/lane global -> LDS. lds base must be wave-uniform; data lands at base + lane*16.
#define GLD16(gp, lp) __builtin_amdgcn_global_load_lds( \
    (const __attribute__((address_space(1))) void*)(gp), \
    (__attribute__((address_space(3))) void*)(lp), 16, 0, 0)

// ---------------------------------------------------------------------------
// Prepass: cast x, w1, w2, w3 fp32 -> bf16. Segmented grid: block ranges own
// one array each; float8 per thread per iter (2x float4 load, 1x 16B store).
// blocks: x [0,512) | w1 [512,2560) | w2 [2560,4608) | w3 [4608,6656)
// ---------------------------------------------------------------------------
#define CVT_XBLK 512
#define CVT_WBLK 2048
#define CVT_NBLK (CVT_XBLK + 3 * CVT_WBLK)

__global__ __launch_bounds__(256) void cvt_all2(
    const float* __restrict__ x, const float* __restrict__ w1,
    const float* __restrict__ w2, const float* __restrict__ w3,
    u16* __restrict__ xb, u16* __restrict__ w1b,
    u16* __restrict__ w2b, u16* __restrict__ w3b)
{
    int b = blockIdx.x;
    const float* src; u16* dst; int n8; int b0; int nb;
    if (b < CVT_XBLK) {
        src = x; dst = xb; n8 = N_ * D_ / 8; b0 = 0; nb = CVT_XBLK;
    } else if (b < CVT_XBLK + CVT_WBLK) {
        src = w1; dst = w1b; n8 = E_ * H_ * D_ / 8; b0 = CVT_XBLK; nb = CVT_WBLK;
    } else if (b < CVT_XBLK + 2 * CVT_WBLK) {
        src = w2; dst = w2b; n8 = E_ * D_ * H_ / 8; b0 = CVT_XBLK + CVT_WBLK; nb = CVT_WBLK;
    } else {
        src = w3; dst = w3b; n8 = E_ * H_ * D_ / 8; b0 = CVT_XBLK + 2 * CVT_WBLK; nb = CVT_WBLK;
    }
    int t = (b - b0) * 256 + threadIdx.x;
    int stride = nb * 256;
    const float4* s4 = (const float4*)src;
    for (int i = t; i < n8; i += stride) {
        float4 a = s4[i * 2];
        float4 c = s4[i * 2 + 1];
        union { u16 u[8]; bf16x8 v; } o;
        o.u[0] = f2bf(a.x); o.u[1] = f2bf(a.y); o.u[2] = f2bf(a.z); o.u[3] = f2bf(a.w);
        o.u[4] = f2bf(c.x); o.u[5] = f2bf(c.y); o.u[6] = f2bf(c.z); o.u[7] = f2bf(c.w);
        *(bf16x8*)(dst + (size_t)i * 8) = o.v;
    }
}

// ---------------------------------------------------------------------------
// Kernel 1: h = gelu_tanh(x@w1^T) * (x@w3^T), bf16 operands in HBM.
// Tile 128x64 (BM=128 tokens, BN=64 H-cols), BK=32. 4 waves in 2x2:
// wave tile 64x32 -> i=4, j=2, dual acc = 64 AGPRs -> 3 blocks/CU.
// Epilogue: LDS transpose buffer (pitch 72) -> coalesced 16B bf16 stores.
// ---------------------------------------------------------------------------
#define EPIT 72   // epilogue LDS pitch (u16): 144 B rows, 16B-aligned, 2-way banks

__global__ __launch_bounds__(256, 3) void moe_gemm13_fast(
    const u16* __restrict__ xb, const u16* __restrict__ w1b,
    const u16* __restrict__ w3b, const int* __restrict__ ntpe,
    u16* __restrict__ hbuf)
{
    __shared__ u16 smem[128 * EPIT];           // 18432 u16 = 36 KB? no: 18432*2 = 36KB.. see note
    // NOTE: 128*72*2 B = 18.4 KB. Staging aliases the front 16 KB:
    u16* sA  = smem;                           // 128x32 = 4096 el
    u16* sB1 = smem + 4096;                    // 64x32  = 2048 el
    u16* sB2 = smem + 6144;                    // 64x32  = 2048 el

    const int tid = threadIdx.x;
    const int m0 = blockIdx.y * 128, n0 = blockIdx.x * 64;
    const int e = expert_of(ntpe, m0);
    const int wave = tid >> 6, lane = tid & 63;
    const int wm = (wave >> 1) * 64, wn = (wave & 1) * 32;
    const int fr = lane & 15, quad = lane >> 4;

    const u16* Ag  = xb  + (size_t)m0 * D_;
    const u16* B1g = w1b + ((size_t)e * H_ + n0) * D_;
    const u16* B2g = w3b + ((size_t)e * H_ + n0) * D_;

    // staging geometry: 16B/lane, 4 lanes per 64B row-chunk
    const int srA = wave * 32 + (lane >> 2);   // A rows (+c*16)
    const int srB = wave * 16 + (lane >> 2);   // B rows
    const int scol = (lane & 3) * 8;

    f32x4 accg[4][2], accu[4][2];
    #pragma unroll
    for (int i = 0; i < 4; ++i)
        #pragma unroll
        for (int j = 0; j < 2; ++j) {
            accg[i][j] = (f32x4){0.f, 0.f, 0.f, 0.f};
            accu[i][j] = (f32x4){0.f, 0.f, 0.f, 0.f};
        }

    for (int k0 = 0; k0 < D_; k0 += 32) {
        #pragma unroll
        for (int c = 0; c < 2; ++c)
            GLD16(Ag + (size_t)(srA + c * 16) * D_ + k0 + scol, sA + (wave * 32 + c * 16) * 32);
        GLD16(B1g + (size_t)srB * D_ + k0 + scol, sB1 + wave * 16 * 32);
        GLD16(B2g + (size_t)srB * D_ + k0 + scol, sB2 + wave * 16 * 32);
        __syncthreads();

        bf16x8 fa[4], fb1[2], fb2[2];
        #pragma unroll
        for (int i = 0; i < 4; ++i)
            fa[i] = *(const bf16x8*)(&sA[(wm + i * 16 + fr) * 32 + quad * 8]);
        #pragma unroll
        for (int j = 0; j < 2; ++j) {
            fb1[j] = *(const bf16x8*)(&sB1[(wn + j * 16 + fr) * 32 + quad * 8]);
            fb2[j] = *(const bf16x8*)(&sB2[(wn + j * 16 + fr) * 32 + quad * 8]);
        }
        #pragma unroll
        for (int i = 0; i < 4; ++i)
            #pragma unroll
            for (int j = 0; j < 2; ++j) {
                accg[i][j] = __builtin_amdgcn_mfma_f32_16x16x32_bf16(fa[i], fb1[j], accg[i][j], 0, 0, 0);
                accu[i][j] = __builtin_amdgcn_mfma_f32_16x16x32_bf16(fa[i], fb2[j], accu[i][j], 0, 0, 0);
            }
        __syncthreads();
    }

    // Epilogue: gelu(g)*u -> LDS tile (row-major, pitch EPIT) -> coalesced stores
    #pragma unroll
    for (int i = 0; i < 4; ++i) {
        int rl = wm + i * 16 + quad * 4;
        #pragma unroll
        for (int j = 0; j < 2; ++j) {
            int cl = wn + j * 16 + fr;
            #pragma unroll
            for (int r = 0; r < 4; ++r) {
                float hv = gelu_tanh(accg[i][j][r]) * accu[i][j][r];
                smem[(rl + r) * EPIT + cl] = f2bf(hv);
            }
        }
    }
    __syncthreads();
    // 128x64 tile = 8192 el; 256 threads x 8 el x 4 iters, 16B stores
    #pragma unroll
    for (int it = 0; it < 4; ++it) {
        int chunk = it * 256 + tid;          // [0,1024)
        int row = chunk >> 3;
        int col = (chunk & 7) * 8;
        bf16x8 v = *(const bf16x8*)(&smem[row * EPIT + col]);
        *(bf16x8*)(&hbuf[(size_t)(m0 + row) * H_ + n0 + col]) = v;
    }
}

// ---------------------------------------------------------------------------
// Kernel 2: out = h @ w2^T (K = 4096), bf16 in HBM, out fp32. m97 structure.
// ---------------------------------------------------------------------------
__global__ __launch_bounds__(256, 3) void moe_gemm2_fast(
    const u16* __restrict__ hbuf, const u16* __restrict__ w2b,
    const int* __restrict__ ntpe, float* __restrict__ out)
{
    __shared__ u16 sA[128 * 32], sB[128 * 32];
    const int tid = threadIdx.x;
    const int m0 = blockIdx.y * 128, n0 = blockIdx.x * 128;
    const int e = expert_of(ntpe, m0);
    const int wave = tid >> 6, lane = tid & 63;
    const int wm = (wave >> 1) * 64, wn = (wave & 1) * 64;
    const int fr = lane & 15, quad = lane >> 4;

    const u16* Ag = hbuf + (size_t)m0 * H_;
    const u16* Bg = w2b + ((size_t)e * D_ + n0) * H_;

    const int srow = wave * 32 + (lane >> 2);
    const int scol = (lane & 3) * 8;

    f32x4 acc[4][4];
    #pragma unroll
    for (int i = 0; i < 4; ++i)
        #pragma unroll
        for (int j = 0; j < 4; ++j)
            acc[i][j] = (f32x4){0.f, 0.f, 0.f, 0.f};

    for (int k0 = 0; k0 < H_; k0 += 32) {
        #pragma unroll
        for (int c = 0; c < 2; ++c) {
            size_t go = (size_t)(srow + c * 16) * H_ + k0 + scol;
            int lb = (wave * 2 + c) * 16 * 32;
            GLD16(Ag + go, &sA[lb]);
            GLD16(Bg + go, &sB[lb]);
        }
        __syncthreads();

        bf16x8 fa[4], fb[4];
        #pragma unroll
        for (int i = 0; i < 4; ++i) {
            fa[i] = *(const bf16x8*)(&sA[(wm + i * 16 + fr) * 32 + quad * 8]);
            fb[i] = *(const bf16x8*)(&sB[(wn + i * 16 + fr) * 32 + quad * 8]);
        }
        #pragma unroll
        for (int i = 0; i < 4; ++i)
            #pragma unroll
            for (int j = 0; j < 4; ++j)
                acc[i][j] = __builtin_amdgcn_mfma_f32_16x16x32_bf16(fa[i], fb[j], acc[i][j], 0, 0, 0);
        __syncthreads();
    }

    #pragma unroll
    for (int i = 0; i < 4; ++i) {
        int rowb = m0 + wm + i * 16 + quad * 4;
        #pragma unroll
        for (int j = 0; j < 4; ++j) {
            int col = n0 + wn + j * 16 + fr;
            #pragma unroll
            for (int r = 0; r < 4; ++r)
                out[(size_t)(rowb + r) * D_ + col] = acc[i][j][r];
        }
    }
}

// ---------------------------------------------------------------------------
// Fallback (round-1) kernels: fused fp32->bf16 staging, used if ws too small
// ---------------------------------------------------------------------------
#define LDSP 40

__global__ __launch_bounds__(256, 2) void moe_gemm13_slow(
    const float* __restrict__ x, const float* __restrict__ w1,
    const float* __restrict__ w3, const int* __restrict__ ntpe,
    u16* __restrict__ hbuf)
{
    const int tid = threadIdx.x;
    const int m0 = blockIdx.y * 128, n0 = blockIdx.x * 128;
    const int e = expert_of(ntpe, m0);
    __shared__ u16 sA[128][LDSP]; __shared__ u16 sB1[128][LDSP]; __shared__ u16 sB2[128][LDSP];
    const int wave = tid >> 6, lane = tid & 63;
    const int wm = (wave >> 1) * 64, wn = (wave & 1) * 64;
    const int fr = lane & 15, quad = lane >> 4;
    f32x4 accg[4][4], accu[4][4];
    #pragma unroll
    for (int i = 0; i < 4; ++i)
        #pragma unroll
        for (int j = 0; j < 4; ++j) {
            accg[i][j] = (f32x4){0.f,0.f,0.f,0.f}; accu[i][j] = (f32x4){0.f,0.f,0.f,0.f};
        }
    const float* Ab  = x  + (size_t)m0 * D_;
    const float* B1b = w1 + ((size_t)e * H_ + n0) * D_;
    const float* B2b = w3 + ((size_t)e * H_ + n0) * D_;
    for (int k0 = 0; k0 < D_; k0 += 32) {
        #pragma unroll
        for (int s = 0; s < 4; ++s) {
            int idx = s * 256 + tid;
            int row = idx >> 3, col = (idx & 7) * 4;
            size_t go = (size_t)row * D_ + k0 + col;
            st_bf4(&sA[row][col],  *(const float4*)(Ab + go));
            st_bf4(&sB1[row][col], *(const float4*)(B1b + go));
            st_bf4(&sB2[row][col], *(const float4*)(B2b + go));
        }
        __syncthreads();
        bf16x8 fa[4], fb1[4], fb2[4];
        #pragma unroll
        for (int i = 0; i < 4; ++i) {
            fa[i]  = *(const bf16x8*)(&sA[wm + i * 16 + fr][quad * 8]);
            fb1[i] = *(const bf16x8*)(&sB1[wn + i * 16 + fr][quad * 8]);
            fb2[i] = *(const bf16x8*)(&sB2[wn + i * 16 + fr][quad * 8]);
        }
        #pragma unroll
        for (int i = 0; i < 4; ++i)
            #pragma unroll
            for (int j = 0; j < 4; ++j) {
                accg[i][j] = __builtin_amdgcn_mfma_f32_16x16x32_bf16(fa[i], fb1[j], accg[i][j], 0, 0, 0);
                accu[i][j] = __builtin_amdgcn_mfma_f32_16x16x32_bf16(fa[i], fb2[j], accu[i][j], 0, 0, 0);
            }
        __syncthreads();
    }
    #pragma unroll
    for (int i = 0; i < 4; ++i) {
        int rowb = m0 + wm + i * 16 + quad * 4;
        #pragma unroll
        for (int j = 0; j < 4; ++j) {
            int col = n0 + wn + j * 16 + fr;
            #pragma unroll
            for (int r = 0; r < 4; ++r)
                hbuf[(size_t)(rowb + r) * H_ + col] = f2bf(gelu_tanh(accg[i][j][r]) * accu[i][j][r]);
        }
    }
}

__global__ __launch_bounds__(256, 2) void moe_gemm2_slow(
    const u16* __restrict__ hbuf, const float* __restrict__ w2,
    const int* __restrict__ ntpe, float* __restrict__ out)
{
    const int tid = threadIdx.x;
    const int m0 = blockIdx.y * 128, n0 = blockIdx.x * 128;
    const int e = expert_of(ntpe, m0);
    __shared__ u16 sA[128][LDSP]; __shared__ u16 sB[128][LDSP];
    const int wave = tid >> 6, lane = tid & 63;
    const int wm = (wave >> 1) * 64, wn = (wave & 1) * 64;
    const int fr = lane & 15, quad = lane >> 4;
    f32x4 acc[4][4];
    #pragma unroll
    for (int i = 0; i < 4; ++i)
        #pragma unroll
        for (int j = 0; j < 4; ++j) acc[i][j] = (f32x4){0.f,0.f,0.f,0.f};
    const u16* Ab = hbuf + (size_t)m0 * H_;
    const float* Bb = w2 + ((size_t)e * D_ + n0) * H_;
    for (int k0 = 0; k0 < H_; k0 += 32) {
        #pragma unroll
        for (int s = 0; s < 2; ++s) {
            int idx = s * 256 + tid;
            int row = idx >> 2, col = (idx & 3) * 8;
            *(bf16x8*)(&sA[row][col]) = *(const bf16x8*)(Ab + (size_t)row * H_ + k0 + col);
        }
        #pragma unroll
        for (int s = 0; s < 4; ++s) {
            int idx = s * 256 + tid;
            int row = idx >> 3, col = (idx & 7) * 4;
            st_bf4(&sB[row][col], *(const float4*)(Bb + (size_t)row * H_ + k0 + col));
        }
        __syncthreads();
        bf16x8 fa[4], fb[4];
        #pragma unroll
        for (int i = 0; i < 4; ++i) {
            fa[i] = *(const bf16x8*)(&sA[wm + i * 16 + fr][quad * 8]);
            fb[i] = *(const bf16x8*)(&sB[wn + i * 16 + fr][quad * 8]);
        }
        #pragma unroll
        for (int i = 0; i < 4; ++i)
            #pragma unroll
            for (int j = 0; j < 4; ++j)
                acc[i][j] = __builtin_amdgcn_mfma_f32_16x16x32_bf16(fa[i], fb[j], acc[i][j], 0, 0, 0);
        __syncthreads();
    }
    #pragma unroll
    for (int i = 0; i < 4; ++i) {
        int rowb = m0 + wm + i * 16 + quad * 4;
        #pragma unroll
        for (int j = 0; j < 4; ++j) {
            int col = n0 + wn + j * 16 + fr;
            #pragma unroll
            for (int r = 0; r < 4; ++r)
                out[(size_t)(rowb + r) * D_ + col] = acc[i][j][r];
        }
    }
}

extern "C" void kernel_launch(void* const* d_in, const int* in_sizes, int n_in,
                              void* d_out, int out_size, void* d_ws, size_t ws_size,
                              hipStream_t stream) {
    const float* x  = (const float*)d_in[0];
    const float* w1 = (const float*)d_in[1];
    const float* w2 = (const float*)d_in[2];
    const float* w3 = (const float*)d_in[3];
    const int* ntpe = (const int*)d_in[4];
    float* out = (float*)d_out;

    // ws layout (bytes): xb 16M | w1b 64M | w3b 64M | w2b 64M | h 64M = 272 MB
    const size_t SZ_XB = (size_t)N_ * D_ * 2;
    const size_t SZ_W  = (size_t)E_ * H_ * D_ * 2;
    const size_t SZ_H  = (size_t)N_ * H_ * 2;
    const size_t NEED  = SZ_XB + 3 * SZ_W + SZ_H;

    if (ws_size >= NEED) {
        char* p = (char*)d_ws;
        u16* xb  = (u16*)p;                 p += SZ_XB;
        u16* w1b = (u16*)p;                 p += SZ_W;
        u16* w3b = (u16*)p;                 p += SZ_W;
        u16* w2b = (u16*)p;                 p += SZ_W;
        u16* hb  = (u16*)p;

        cvt_all2<<<CVT_NBLK, 256, 0, stream>>>(x, w1, w2, w3, xb, w1b, w2b, w3b);

        dim3 g1(H_ / 64, N_ / 128);   // (64, 64)
        moe_gemm13_fast<<<g1, 256, 0, stream>>>(xb, w1b, w3b, ntpe, hb);

        dim3 g2(D_ / 128, N_ / 128);  // (8, 64)
        moe_gemm2_fast<<<g2, 256, 0, stream>>>(hb, w2b, ntpe, out);
    } else {
        u16* hb = (u16*)d_ws;  // 64 MB
        dim3 g1(H_ / 128, N_ / 128);
        moe_gemm13_slow<<<g1, 256, 0, stream>>>(x, w1, w3, ntpe, hb);
        dim3 g2(D_ / 128, N_ / 128);
        moe_gemm2_slow<<<g2, 256, 0, stream>>>(hb, w2, ntpe, out);
    }
}

// Round 4
// 644.531 us; speedup vs baseline: 1.3411x; 1.0946x over previous
//
#include <hip/hip_runtime.h>
#include <hip/hip_bf16.h>

#define E_ 8
#define D_ 1024
#define H_ 4096
#define N_ 8192

typedef __attribute__((ext_vector_type(8))) short bf16x8;   // MFMA A/B frag: 8 bf16 = 4 VGPRs
typedef __attribute__((ext_vector_type(4))) float f32x4;    // MFMA C/D frag
typedef unsigned short u16;

// fp32 -> bf16 round-to-nearest-even
static __device__ __forceinline__ u16 f2bf(float f) {
    unsigned int u = __float_as_uint(f);
    u += 0x7fffu + ((u >> 16) & 1u);
    return (u16)(u >> 16);
}

static __device__ __forceinline__ void st_bf4(u16* p, float4 v) {
    union { u16 u[4]; unsigned long long ll; } t;
    t.u[0] = f2bf(v.x); t.u[1] = f2bf(v.y); t.u[2] = f2bf(v.z); t.u[3] = f2bf(v.w);
    *(unsigned long long*)p = t.ll;
}

static __device__ __forceinline__ float gelu_tanh(float x) {
    float x3 = x * x * x;
    float z = 0.7978845608028654f * (x + 0.044715f * x3);
    float t = 1.0f - 2.0f / (1.0f + __expf(2.0f * z));  // tanh(z)
    return 0.5f * x * (1.0f + t);
}

static __device__ __forceinline__ int expert_of(const int* __restrict__ ntpe, int row) {
    int acc = 0;
    #pragma unroll
    for (int i = 0; i < E_; ++i) {
        acc += ntpe[i];
        if (row < acc) return i;
    }
    return E_ - 1;
}

// async 16B/lane global -> LDS. lds base must be wave-uniform; data lands at base + lane*16.
#define GLD16(gp, lp) __builtin_amdgcn_global_load_lds( \
    (const __attribute__((address_space(1))) void*)(gp), \
    (__attribute__((address_space(3))) void*)(lp), 16, 0, 0)

// ---------------------------------------------------------------------------
// Prepass: cast x, w1, w2, w3 fp32 -> bf16. Segmented grid; float8/thread.
// ---------------------------------------------------------------------------
#define CVT_XBLK 512
#define CVT_WBLK 2048
#define CVT_NBLK (CVT_XBLK + 3 * CVT_WBLK)

__global__ __launch_bounds__(256) void cvt_all2(
    const float* __restrict__ x, const float* __restrict__ w1,
    const float* __restrict__ w2, const float* __restrict__ w3,
    u16* __restrict__ xb, u16* __restrict__ w1b,
    u16* __restrict__ w2b, u16* __restrict__ w3b)
{
    int b = blockIdx.x;
    const float* src; u16* dst; int n8; int b0; int nb;
    if (b < CVT_XBLK) {
        src = x; dst = xb; n8 = N_ * D_ / 8; b0 = 0; nb = CVT_XBLK;
    } else if (b < CVT_XBLK + CVT_WBLK) {
        src = w1; dst = w1b; n8 = E_ * H_ * D_ / 8; b0 = CVT_XBLK; nb = CVT_WBLK;
    } else if (b < CVT_XBLK + 2 * CVT_WBLK) {
        src = w2; dst = w2b; n8 = E_ * D_ * H_ / 8; b0 = CVT_XBLK + CVT_WBLK; nb = CVT_WBLK;
    } else {
        src = w3; dst = w3b; n8 = E_ * H_ * D_ / 8; b0 = CVT_XBLK + 2 * CVT_WBLK; nb = CVT_WBLK;
    }
    int t = (b - b0) * 256 + threadIdx.x;
    int stride = nb * 256;
    const float4* s4 = (const float4*)src;
    for (int i = t; i < n8; i += stride) {
        float4 a = s4[i * 2];
        float4 c = s4[i * 2 + 1];
        union { u16 u[8]; bf16x8 v; } o;
        o.u[0] = f2bf(a.x); o.u[1] = f2bf(a.y); o.u[2] = f2bf(a.z); o.u[3] = f2bf(a.w);
        o.u[4] = f2bf(c.x); o.u[5] = f2bf(c.y); o.u[6] = f2bf(c.z); o.u[7] = f2bf(c.w);
        *(bf16x8*)(dst + (size_t)i * 8) = o.v;
    }
}

// ---------------------------------------------------------------------------
// LDS swizzle: row r (128 B = 8x16B chunks) stores global chunk c at slot
// c ^ (r & 7). Frag read for lane(fr,quad), k-half kh: slot (quad+4kh)^(fr&7)
// -> 16B-slot group covers all 8 groups twice per quad-group => conflict-free.
// Staging: lane L -> row_rel L>>3, slot L&7, source chunk (L&7)^((L>>3)&7).
// ---------------------------------------------------------------------------

// Kernel 1: h = gelu_tanh(x@w1^T) * (x@w3^T). BM=128, BN=64, BK=64.
// 4 waves 2x2 (wave tile 64x32). Dual acc 4x2 = 64 AGPRs. 32 KB LDS, 3 blk/CU.
#define EPIT 72   // epilogue LDS pitch (u16)

__global__ __launch_bounds__(256, 3) void moe_gemm13_fast(
    const u16* __restrict__ xb, const u16* __restrict__ w1b,
    const u16* __restrict__ w3b, const int* __restrict__ ntpe,
    u16* __restrict__ hbuf)
{
    __shared__ u16 smem[16384];      // 32 KB staging; epilogue reuses 9216 el
    u16* sA  = smem;                 // 128x64
    u16* sB1 = smem + 8192;          // 64x64
    u16* sB2 = smem + 12288;         // 64x64

    const int tid = threadIdx.x;
    const int m0 = blockIdx.y * 128, n0 = blockIdx.x * 64;
    const int e = expert_of(ntpe, m0);
    const int wave = tid >> 6, lane = tid & 63;
    const int wm = (wave >> 1) * 64, wn = (wave & 1) * 32;
    const int fr = lane & 15, quad = lane >> 4;
    const int sw = fr & 7;

    const u16* Ag  = xb  + (size_t)m0 * D_;
    const u16* B1g = w1b + ((size_t)e * H_ + n0) * D_;
    const u16* B2g = w3b + ((size_t)e * H_ + n0) * D_;

    const int srr = lane >> 3;                 // row within 8-row group
    const int scg = ((lane & 7) ^ srr) * 8;    // swizzled source col (elements)

    f32x4 accg[4][2], accu[4][2];
    #pragma unroll
    for (int i = 0; i < 4; ++i)
        #pragma unroll
        for (int j = 0; j < 2; ++j) {
            accg[i][j] = (f32x4){0.f, 0.f, 0.f, 0.f};
            accu[i][j] = (f32x4){0.f, 0.f, 0.f, 0.f};
        }

    for (int k0 = 0; k0 < D_; k0 += 64) {
        #pragma unroll
        for (int c = 0; c < 4; ++c)
            GLD16(Ag + (size_t)(wave * 32 + c * 8 + srr) * D_ + k0 + scg,
                  sA + (wave * 32 + c * 8) * 64);
        #pragma unroll
        for (int c = 0; c < 2; ++c) {
            GLD16(B1g + (size_t)(wave * 16 + c * 8 + srr) * D_ + k0 + scg,
                  sB1 + (wave * 16 + c * 8) * 64);
            GLD16(B2g + (size_t)(wave * 16 + c * 8 + srr) * D_ + k0 + scg,
                  sB2 + (wave * 16 + c * 8) * 64);
        }
        __syncthreads();

        #pragma unroll
        for (int kh = 0; kh < 2; ++kh) {
            const int ks = ((quad + kh * 4) ^ sw) * 8;
            bf16x8 fa[4], fb1[2], fb2[2];
            #pragma unroll
            for (int i = 0; i < 4; ++i)
                fa[i] = *(const bf16x8*)(&sA[(wm + i * 16 + fr) * 64 + ks]);
            #pragma unroll
            for (int j = 0; j < 2; ++j) {
                fb1[j] = *(const bf16x8*)(&sB1[(wn + j * 16 + fr) * 64 + ks]);
                fb2[j] = *(const bf16x8*)(&sB2[(wn + j * 16 + fr) * 64 + ks]);
            }
            #pragma unroll
            for (int i = 0; i < 4; ++i)
                #pragma unroll
                for (int j = 0; j < 2; ++j) {
                    accg[i][j] = __builtin_amdgcn_mfma_f32_16x16x32_bf16(fa[i], fb1[j], accg[i][j], 0, 0, 0);
                    accu[i][j] = __builtin_amdgcn_mfma_f32_16x16x32_bf16(fa[i], fb2[j], accu[i][j], 0, 0, 0);
                }
        }
        __syncthreads();
    }

    // Epilogue: gelu(g)*u -> LDS tile (pitch EPIT) -> coalesced 16B stores
    #pragma unroll
    for (int i = 0; i < 4; ++i) {
        int rl = wm + i * 16 + quad * 4;
        #pragma unroll
        for (int j = 0; j < 2; ++j) {
            int cl = wn + j * 16 + fr;
            #pragma unroll
            for (int r = 0; r < 4; ++r) {
                float hv = gelu_tanh(accg[i][j][r]) * accu[i][j][r];
                smem[(rl + r) * EPIT + cl] = f2bf(hv);
            }
        }
    }
    __syncthreads();
    #pragma unroll
    for (int it = 0; it < 4; ++it) {
        int chunk = it * 256 + tid;          // [0,1024)
        int row = chunk >> 3;
        int col = (chunk & 7) * 8;
        bf16x8 v = *(const bf16x8*)(&smem[row * EPIT + col]);
        *(bf16x8*)(&hbuf[(size_t)(m0 + row) * H_ + n0 + col]) = v;
    }
}

// Kernel 2: out = h @ w2^T (K=4096). BM=128, BN=128, BK=64, swizzled, 32 KB LDS.
__global__ __launch_bounds__(256, 3) void moe_gemm2_fast(
    const u16* __restrict__ hbuf, const u16* __restrict__ w2b,
    const int* __restrict__ ntpe, float* __restrict__ out)
{
    __shared__ u16 smem[16384];
    u16* sA = smem;                  // 128x64
    u16* sB = smem + 8192;           // 128x64

    const int tid = threadIdx.x;
    const int m0 = blockIdx.y * 128, n0 = blockIdx.x * 128;
    const int e = expert_of(ntpe, m0);
    const int wave = tid >> 6, lane = tid & 63;
    const int wm = (wave >> 1) * 64, wn = (wave & 1) * 64;
    const int fr = lane & 15, quad = lane >> 4;
    const int sw = fr & 7;

    const u16* Ag = hbuf + (size_t)m0 * H_;
    const u16* Bg = w2b + ((size_t)e * D_ + n0) * H_;

    const int srr = lane >> 3;
    const int scg = ((lane & 7) ^ srr) * 8;

    f32x4 acc[4][4];
    #pragma unroll
    for (int i = 0; i < 4; ++i)
        #pragma unroll
        for (int j = 0; j < 4; ++j)
            acc[i][j] = (f32x4){0.f, 0.f, 0.f, 0.f};

    for (int k0 = 0; k0 < H_; k0 += 64) {
        #pragma unroll
        for (int c = 0; c < 4; ++c) {
            GLD16(Ag + (size_t)(wave * 32 + c * 8 + srr) * H_ + k0 + scg,
                  sA + (wave * 32 + c * 8) * 64);
            GLD16(Bg + (size_t)(wave * 32 + c * 8 + srr) * H_ + k0 + scg,
                  sB + (wave * 32 + c * 8) * 64);
        }
        __syncthreads();

        #pragma unroll
        for (int kh = 0; kh < 2; ++kh) {
            const int ks = ((quad + kh * 4) ^ sw) * 8;
            bf16x8 fa[4], fb[4];
            #pragma unroll
            for (int i = 0; i < 4; ++i) {
                fa[i] = *(const bf16x8*)(&sA[(wm + i * 16 + fr) * 64 + ks]);
                fb[i] = *(const bf16x8*)(&sB[(wn + i * 16 + fr) * 64 + ks]);
            }
            #pragma unroll
            for (int i = 0; i < 4; ++i)
                #pragma unroll
                for (int j = 0; j < 4; ++j)
                    acc[i][j] = __builtin_amdgcn_mfma_f32_16x16x32_bf16(fa[i], fb[j], acc[i][j], 0, 0, 0);
        }
        __syncthreads();
    }

    #pragma unroll
    for (int i = 0; i < 4; ++i) {
        int rowb = m0 + wm + i * 16 + quad * 4;
        #pragma unroll
        for (int j = 0; j < 4; ++j) {
            int col = n0 + wn + j * 16 + fr;
            #pragma unroll
            for (int r = 0; r < 4; ++r)
                out[(size_t)(rowb + r) * D_ + col] = acc[i][j][r];
        }
    }
}

// ---------------------------------------------------------------------------
// Fallback (round-1) kernels, used if ws too small
// ---------------------------------------------------------------------------
#define LDSP 40

__global__ __launch_bounds__(256, 2) void moe_gemm13_slow(
    const float* __restrict__ x, const float* __restrict__ w1,
    const float* __restrict__ w3, const int* __restrict__ ntpe,
    u16* __restrict__ hbuf)
{
    const int tid = threadIdx.x;
    const int m0 = blockIdx.y * 128, n0 = blockIdx.x * 128;
    const int e = expert_of(ntpe, m0);
    __shared__ u16 sA[128][LDSP]; __shared__ u16 sB1[128][LDSP]; __shared__ u16 sB2[128][LDSP];
    const int wave = tid >> 6, lane = tid & 63;
    const int wm = (wave >> 1) * 64, wn = (wave & 1) * 64;
    const int fr = lane & 15, quad = lane >> 4;
    f32x4 accg[4][4], accu[4][4];
    #pragma unroll
    for (int i = 0; i < 4; ++i)
        #pragma unroll
        for (int j = 0; j < 4; ++j) {
            accg[i][j] = (f32x4){0.f,0.f,0.f,0.f}; accu[i][j] = (f32x4){0.f,0.f,0.f,0.f};
        }
    const float* Ab  = x  + (size_t)m0 * D_;
    const float* B1b = w1 + ((size_t)e * H_ + n0) * D_;
    const float* B2b = w3 + ((size_t)e * H_ + n0) * D_;
    for (int k0 = 0; k0 < D_; k0 += 32) {
        #pragma unroll
        for (int s = 0; s < 4; ++s) {
            int idx = s * 256 + tid;
            int row = idx >> 3, col = (idx & 7) * 4;
            size_t go = (size_t)row * D_ + k0 + col;
            st_bf4(&sA[row][col],  *(const float4*)(Ab + go));
            st_bf4(&sB1[row][col], *(const float4*)(B1b + go));
            st_bf4(&sB2[row][col], *(const float4*)(B2b + go));
        }
        __syncthreads();
        bf16x8 fa[4], fb1[4], fb2[4];
        #pragma unroll
        for (int i = 0; i < 4; ++i) {
            fa[i]  = *(const bf16x8*)(&sA[wm + i * 16 + fr][quad * 8]);
            fb1[i] = *(const bf16x8*)(&sB1[wn + i * 16 + fr][quad * 8]);
            fb2[i] = *(const bf16x8*)(&sB2[wn + i * 16 + fr][quad * 8]);
        }
        #pragma unroll
        for (int i = 0; i < 4; ++i)
            #pragma unroll
            for (int j = 0; j < 4; ++j) {
                accg[i][j] = __builtin_amdgcn_mfma_f32_16x16x32_bf16(fa[i], fb1[j], accg[i][j], 0, 0, 0);
                accu[i][j] = __builtin_amdgcn_mfma_f32_16x16x32_bf16(fa[i], fb2[j], accu[i][j], 0, 0, 0);
            }
        __syncthreads();
    }
    #pragma unroll
    for (int i = 0; i < 4; ++i) {
        int rowb = m0 + wm + i * 16 + quad * 4;
        #pragma unroll
        for (int j = 0; j < 4; ++j) {
            int col = n0 + wn + j * 16 + fr;
            #pragma unroll
            for (int r = 0; r < 4; ++r)
                hbuf[(size_t)(rowb + r) * H_ + col] = f2bf(gelu_tanh(accg[i][j][r]) * accu[i][j][r]);
        }
    }
}

__global__ __launch_bounds__(256, 2) void moe_gemm2_slow(
    const u16* __restrict__ hbuf, const float* __restrict__ w2,
    const int* __restrict__ ntpe, float* __restrict__ out)
{
    const int tid = threadIdx.x;
    const int m0 = blockIdx.y * 128, n0 = blockIdx.x * 128;
    const int e = expert_of(ntpe, m0);
    __shared__ u16 sA[128][LDSP]; __shared__ u16 sB[128][LDSP];
    const int wave = tid >> 6, lane = tid & 63;
    const int wm = (wave >> 1) * 64, wn = (wave & 1) * 64;
    const int fr = lane & 15, quad = lane >> 4;
    f32x4 acc[4][4];
    #pragma unroll
    for (int i = 0; i < 4; ++i)
        #pragma unroll
        for (int j = 0; j < 4; ++j) acc[i][j] = (f32x4){0.f,0.f,0.f,0.f};
    const u16* Ab = hbuf + (size_t)m0 * H_;
    const float* Bb = w2 + ((size_t)e * D_ + n0) * H_;
    for (int k0 = 0; k0 < H_; k0 += 32) {
        #pragma unroll
        for (int s = 0; s < 2; ++s) {
            int idx = s * 256 + tid;
            int row = idx >> 2, col = (idx & 3) * 8;
            *(bf16x8*)(&sA[row][col]) = *(const bf16x8*)(Ab + (size_t)row * H_ + k0 + col);
        }
        #pragma unroll
        for (int s = 0; s < 4; ++s) {
            int idx = s * 256 + tid;
            int row = idx >> 3, col = (idx & 7) * 4;
            st_bf4(&sB[row][col], *(const float4*)(Bb + (size_t)row * H_ + k0 + col));
        }
        __syncthreads();
        bf16x8 fa[4], fb[4];
        #pragma unroll
        for (int i = 0; i < 4; ++i) {
            fa[i] = *(const bf16x8*)(&sA[wm + i * 16 + fr][quad * 8]);
            fb[i] = *(const bf16x8*)(&sB[wn + i * 16 + fr][quad * 8]);
        }
        #pragma unroll
        for (int i = 0; i < 4; ++i)
            #pragma unroll
            for (int j = 0; j < 4; ++j)
                acc[i][j] = __builtin_amdgcn_mfma_f32_16x16x32_bf16(fa[i], fb[j], acc[i][j], 0, 0, 0);
        __syncthreads();
    }
    #pragma unroll
    for (int i = 0; i < 4; ++i) {
        int rowb = m0 + wm + i * 16 + quad * 4;
        #pragma unroll
        for (int j = 0; j < 4; ++j) {
            int col = n0 + wn + j * 16 + fr;
            #pragma unroll
            for (int r = 0; r < 4; ++r)
                out[(size_t)(rowb + r) * D_ + col] = acc[i][j][r];
        }
    }
}

extern "C" void kernel_launch(void* const* d_in, const int* in_sizes, int n_in,
                              void* d_out, int out_size, void* d_ws, size_t ws_size,
                              hipStream_t stream) {
    const float* x  = (const float*)d_in[0];
    const float* w1 = (const float*)d_in[1];
    const float* w2 = (const float*)d_in[2];
    const float* w3 = (const float*)d_in[3];
    const int* ntpe = (const int*)d_in[4];
    float* out = (float*)d_out;

    // ws layout (bytes): xb 16M | w1b 64M | w3b 64M | w2b 64M | h 64M = 272 MB
    const size_t SZ_XB = (size_t)N_ * D_ * 2;
    const size_t SZ_W  = (size_t)E_ * H_ * D_ * 2;
    const size_t SZ_H  = (size_t)N_ * H_ * 2;
    const size_t NEED  = SZ_XB + 3 * SZ_W + SZ_H;

    if (ws_size >= NEED) {
        char* p = (char*)d_ws;
        u16* xb  = (u16*)p;                 p += SZ_XB;
        u16* w1b = (u16*)p;                 p += SZ_W;
        u16* w3b = (u16*)p;                 p += SZ_W;
        u16* w2b = (u16*)p;                 p += SZ_W;
        u16* hb  = (u16*)p;

        cvt_all2<<<CVT_NBLK, 256, 0, stream>>>(x, w1, w2, w3, xb, w1b, w2b, w3b);

        dim3 g1(H_ / 64, N_ / 128);   // (64, 64)
        moe_gemm13_fast<<<g1, 256, 0, stream>>>(xb, w1b, w3b, ntpe, hb);

        dim3 g2(D_ / 128, N_ / 128);  // (8, 64)
        moe_gemm2_fast<<<g2, 256, 0, stream>>>(hb, w2b, ntpe, out);
    } else {
        u16* hb = (u16*)d_ws;  // 64 MB
        dim3 g1(H_ / 128, N_ / 128);
        moe_gemm13_slow<<<g1, 256, 0, stream>>>(x, w1, w3, ntpe, hb);
        dim3 g2(D_ / 128, N_ / 128);
        moe_gemm2_slow<<<g2, 256, 0, stream>>>(hb, w2, ntpe, out);
    }
}